// Round 3
// 9938.535 us; speedup vs baseline: 1.0237x; 1.0237x over previous
//
#include <hip/hip_runtime.h>

// Problem constants
#define B_    64
#define C_    4096
#define T_ALL 72
#define T_H   24
#define T_FC  48
#define F_IN  8
#define HID   64
#define NSEQ  (B_ * C_)   // 262144

// ---------------------------------------------------------------------------
// Setup: fold fc_in into W_ih.
//   Wc[j][i] = sum_k W_ih[j][k] * W_in[k][i]   (192 x 4)
//   bc[j]    = b_ih[j] + sum_k W_ih[j][k] * b_in[k]
// ws layout: [0..767] Wc row-major, [768..959] bc
// ---------------------------------------------------------------------------
__global__ __launch_bounds__(192) void setup_kernel(
    const float* __restrict__ W_in, const float* __restrict__ b_in,
    const float* __restrict__ W_ih, const float* __restrict__ b_ih,
    float* __restrict__ ws) {
  int j = threadIdx.x;  // 0..191
  float a0 = 0.f, a1 = 0.f, a2 = 0.f, a3 = 0.f, ab = 0.f;
  for (int k = 0; k < HID; ++k) {
    float w = W_ih[j * HID + k];
    a0 += w * W_in[k * 4 + 0];
    a1 += w * W_in[k * 4 + 1];
    a2 += w * W_in[k * 4 + 2];
    a3 += w * W_in[k * 4 + 3];
    ab += w * b_in[k];
  }
  ws[j * 4 + 0] = a0;
  ws[j * 4 + 1] = a1;
  ws[j * 4 + 2] = a2;
  ws[j * 4 + 3] = a3;
  ws[768 + j] = ab + b_ih[j];
}

// Fast activations: single v_exp_f32 + v_rcp_f32 (~1 ulp, fine vs 2.9e-2 tol)
__device__ __forceinline__ float fast_sigmoid(float x) {
  float e = __builtin_amdgcn_exp2f(-1.4426950408889634f * x);
  return __builtin_amdgcn_rcpf(1.0f + e);
}
// tanh(x) = 2*sigmoid(2x) - 1  (no overflow/NaN at large |x|)
__device__ __forceinline__ float fast_tanh(float x) {
  float e = __builtin_amdgcn_exp2f(-2.8853900817779268f * x);
  return 2.0f * __builtin_amdgcn_rcpf(1.0f + e) - 1.0f;
}

// ---------------------------------------------------------------------------
// Main persistent GRU: one thread = one (b,c) sequence, all 48 steps.
// h[64] + hn[64] live in registers: requires ~150 VGPRs, so we declare
// __launch_bounds__(256, 2) (VGPR cap 256) to prevent the allocator from
// spilling the double-buffer to scratch. (Previous build: 84 VGPRs ->
// ~6.4 GB of scratch writes per dispatch, 68% VALUBusy.)
// W_hh + fused input weights stay in LDS (wave-uniform broadcast reads,
// 0 bank conflicts measured).
// ---------------------------------------------------------------------------
__global__ __launch_bounds__(256, 2) void gru_kernel(
    const float* __restrict__ X, const float* __restrict__ H,
    const float* __restrict__ xn, const float* __restrict__ W_hh,
    const float* __restrict__ b_hh, const float* __restrict__ W_out,
    const float* __restrict__ b_out, const float* __restrict__ ws,
    float* __restrict__ out) {
  __shared__ float sW[192 * 64];   // W_hh row-major: rows 0..63 r, 64..127 z, 128..191 n
  __shared__ float sWc[192 * 4];   // fused input weights
  __shared__ float sbc[192];       // fused input bias
  __shared__ float sbh[192];       // b_hh
  __shared__ float sWo[64];        // W_out

  const int tid = threadIdx.x;
  for (int i = tid; i < 192 * 64; i += 256) sW[i] = W_hh[i];
  for (int i = tid; i < 768; i += 256) sWc[i] = ws[i];
  if (tid < 192) {
    sbc[tid] = ws[768 + tid];
    sbh[tid] = b_hh[tid];
  }
  if (tid < 64) sWo[tid] = W_out[tid];
  __syncthreads();

  const int s = blockIdx.x * 256 + tid;  // sequence id = b*C + c
  const int b = s >> 12;                 // / 4096
  const int c = s & 4095;

  float h[HID];
  const float4* Hp = reinterpret_cast<const float4*>(H + (size_t)s * HID);
#pragma unroll
  for (int k = 0; k < HID / 4; ++k) {
    float4 v = Hp[k];
    h[4 * k + 0] = v.x;
    h[4 * k + 1] = v.y;
    h[4 * k + 2] = v.z;
    h[4 * k + 3] = v.w;
  }
  float xp = xn[s];

  // X[b, 24+t, c, 5..7]
  const float* Xp = X + (((size_t)b * T_ALL + T_H) * C_ + c) * F_IN + 5;
  float* Op = out + (size_t)b * (T_FC * C_) + c;
  const float bo = b_out[0];

  const float4* sW4 = reinterpret_cast<const float4*>(sW);

  // current step's exogenous inputs (prefetched)
  float x1 = Xp[0];
  float x2 = Xp[1];
  float x3 = Xp[2];

#pragma unroll 1
  for (int t = 0; t < T_FC; ++t) {
    // Prefetch next step's inputs; the vmcnt wait lands at the bottom of the
    // body, so the ~500-cycle global latency hides under the ~27k-cycle step.
    const float* Xn = Xp + ((t < T_FC - 1) ? (C_ * F_IN) : 0);
    const float p1 = Xn[0];
    const float p2 = Xn[1];
    const float p3 = Xn[2];

    float hn[HID];
    float o = bo;
#pragma unroll
    for (int u = 0; u < HID; ++u) {
      float gr = sbh[u];
      float gz = sbh[64 + u];
      float gn = sbh[128 + u];
#pragma unroll
      for (int k4 = 0; k4 < HID / 4; ++k4) {
        float4 wr = sW4[u * 16 + k4];
        float4 wz = sW4[(64 + u) * 16 + k4];
        float4 wn = sW4[(128 + u) * 16 + k4];
        gr += h[4 * k4 + 0] * wr.x + h[4 * k4 + 1] * wr.y +
              h[4 * k4 + 2] * wr.z + h[4 * k4 + 3] * wr.w;
        gz += h[4 * k4 + 0] * wz.x + h[4 * k4 + 1] * wz.y +
              h[4 * k4 + 2] * wz.z + h[4 * k4 + 3] * wz.w;
        gn += h[4 * k4 + 0] * wn.x + h[4 * k4 + 1] * wn.y +
              h[4 * k4 + 2] * wn.z + h[4 * k4 + 3] * wn.w;
      }
      float ir = sbc[u] + xp * sWc[4 * u + 0] + x1 * sWc[4 * u + 1] +
                 x2 * sWc[4 * u + 2] + x3 * sWc[4 * u + 3];
      float iz = sbc[64 + u] + xp * sWc[4 * (64 + u) + 0] +
                 x1 * sWc[4 * (64 + u) + 1] + x2 * sWc[4 * (64 + u) + 2] +
                 x3 * sWc[4 * (64 + u) + 3];
      float in_ = sbc[128 + u] + xp * sWc[4 * (128 + u) + 0] +
                  x1 * sWc[4 * (128 + u) + 1] + x2 * sWc[4 * (128 + u) + 2] +
                  x3 * sWc[4 * (128 + u) + 3];
      float r = fast_sigmoid(ir + gr);
      float z = fast_sigmoid(iz + gz);
      float n = fast_tanh(in_ + r * gn);
      float hu = (1.0f - z) * n + z * h[u];
      hn[u] = hu;
      o += hu * sWo[u];
    }
#pragma unroll
    for (int k = 0; k < HID; ++k) h[k] = hn[k];
    *Op = o;
    Op += C_;
    xp = o;  // feedback: x_prev = this step's prediction
    x1 = p1;
    x2 = p2;
    x3 = p3;
    Xp = Xn;
  }
}

extern "C" void kernel_launch(void* const* d_in, const int* in_sizes, int n_in,
                              void* d_out, int out_size, void* d_ws,
                              size_t ws_size, hipStream_t stream) {
  const float* X     = (const float*)d_in[0];
  const float* H     = (const float*)d_in[1];
  const float* xn    = (const float*)d_in[2];
  const float* W_in  = (const float*)d_in[3];
  const float* b_in  = (const float*)d_in[4];
  const float* W_ih  = (const float*)d_in[5];
  const float* W_hh  = (const float*)d_in[6];
  const float* b_ih  = (const float*)d_in[7];
  const float* b_hh  = (const float*)d_in[8];
  const float* W_out = (const float*)d_in[9];
  const float* b_out = (const float*)d_in[10];
  float* out = (float*)d_out;
  float* ws  = (float*)d_ws;

  setup_kernel<<<1, 192, 0, stream>>>(W_in, b_in, W_ih, b_ih, ws);
  gru_kernel<<<NSEQ / 256, 256, 0, stream>>>(X, H, xn, W_hh, b_hh, W_out,
                                             b_out, ws, out);
}

// Round 4
// 9515.970 us; speedup vs baseline: 1.0691x; 1.0444x over previous
//
#include <hip/hip_runtime.h>

// Problem constants
#define B_    64
#define C_    4096
#define T_ALL 72
#define T_H   24
#define T_FC  48
#define F_IN  8
#define HID   64
#define NSEQ  (B_ * C_)   // 262144

// ---------------------------------------------------------------------------
// Setup: fold fc_in into W_ih.
//   Wc[j][i] = sum_k W_ih[j][k] * W_in[k][i]   (192 x 4)
//   bc[j]    = b_ih[j] + sum_k W_ih[j][k] * b_in[k]
// ws layout: [0..767] Wc row-major, [768..959] bc
// ---------------------------------------------------------------------------
__global__ __launch_bounds__(192) void setup_kernel(
    const float* __restrict__ W_in, const float* __restrict__ b_in,
    const float* __restrict__ W_ih, const float* __restrict__ b_ih,
    float* __restrict__ ws) {
  int j = threadIdx.x;  // 0..191
  float a0 = 0.f, a1 = 0.f, a2 = 0.f, a3 = 0.f, ab = 0.f;
  for (int k = 0; k < HID; ++k) {
    float w = W_ih[j * HID + k];
    a0 += w * W_in[k * 4 + 0];
    a1 += w * W_in[k * 4 + 1];
    a2 += w * W_in[k * 4 + 2];
    a3 += w * W_in[k * 4 + 3];
    ab += w * b_in[k];
  }
  ws[j * 4 + 0] = a0;
  ws[j * 4 + 1] = a1;
  ws[j * 4 + 2] = a2;
  ws[j * 4 + 3] = a3;
  ws[768 + j] = ab + b_ih[j];
}

// Fast activations: single v_exp_f32 + v_rcp_f32 (~1 ulp, fine vs tol)
__device__ __forceinline__ float fast_sigmoid(float x) {
  float e = __builtin_amdgcn_exp2f(-1.4426950408889634f * x);
  return __builtin_amdgcn_rcpf(1.0f + e);
}
// tanh(x) = 2*sigmoid(2x) - 1  (no overflow/NaN at large |x|)
__device__ __forceinline__ float fast_tanh(float x) {
  float e = __builtin_amdgcn_exp2f(-2.8853900817779268f * x);
  return 2.0f * __builtin_amdgcn_rcpf(1.0f + e) - 1.0f;
}

#define REP16(M) M(0) M(1) M(2) M(3) M(4) M(5) M(6) M(7) \
                 M(8) M(9) M(10) M(11) M(12) M(13) M(14) M(15)

// ---------------------------------------------------------------------------
// Wave-per-sequence, lane-per-hidden-unit GRU.
//
// Previous structure (thread-per-sequence, h[64]+hn[64] arrays) hit rule #20:
// runtime-indexed per-thread arrays are allocated in scratch (VGPR_Count=84
// measured both with and without a 256-VGPR cap; 6.4 GB scratch writes).
// This version has NO per-thread arrays: lane u's state is one scalar h and
// its 3 W_hh rows live in 48 NAMED float4 registers (macro-expanded, so SROA
// promotion is trivial). h is exchanged through a per-wave 64-float LDS slot:
// write = 2-way bank access (free), reads = same-address broadcast
// (conflict-free). Output o = butterfly shfl_xor reduction; its latency
// overlaps the next step's 192-FMA DOT phase (xp consumed only after it).
// ---------------------------------------------------------------------------
__global__ __launch_bounds__(256, 2) void gru_kernel(
    const float* __restrict__ X, const float* __restrict__ H,
    const float* __restrict__ xn, const float* __restrict__ W_hh,
    const float* __restrict__ b_hh, const float* __restrict__ W_out,
    const float* __restrict__ b_out, const float* __restrict__ ws,
    float* __restrict__ out) {
  __shared__ float sH[4 * HID];  // 4 waves/block, 64 floats each

  const int tid  = threadIdx.x;
  const int lane = tid & 63;
  const int wid  = __builtin_amdgcn_readfirstlane(tid >> 6);  // wave-uniform
  const int s = blockIdx.x * 4 + wid;  // sequence id = b*C + c (SGPR)
  const int b = s >> 12;               // / 4096
  const int c = s & 4095;

  // Per-lane W_hh rows (u, 64+u, 128+u) into named registers: 48 float4.
  // 16B/lane at 256B stride is uncoalesced, but W_hh is 48 KB -> L2-resident
  // after the first waves; one-time cost per wave.
  const float4* Wr4 = reinterpret_cast<const float4*>(W_hh + lane * HID);
  const float4* Wz4 = reinterpret_cast<const float4*>(W_hh + (64 + lane) * HID);
  const float4* Wn4 = reinterpret_cast<const float4*>(W_hh + (128 + lane) * HID);
#define LOADW(i) float4 wr##i = Wr4[i]; float4 wz##i = Wz4[i]; float4 wn##i = Wn4[i];
  REP16(LOADW)
#undef LOADW

  // Fused input weights/biases, per lane.
  const float4* Wc4 = reinterpret_cast<const float4*>(ws);
  const float4 wcr = Wc4[lane];
  const float4 wcz = Wc4[64 + lane];
  const float4 wcn = Wc4[128 + lane];
  // r/z: input bias + recurrent bias merged (always summed). n: kept apart
  // (recurrent part is multiplied by r before adding the input part).
  const float br  = ws[768 + lane] + b_hh[lane];
  const float bz  = ws[832 + lane] + b_hh[64 + lane];
  const float bcn = ws[896 + lane];
  const float bhn = b_hh[128 + lane];
  const float wo  = W_out[lane];
  const float bo  = b_out[0];

  float h  = H[(size_t)s * HID + lane];  // coalesced 256B/wave
  float xp = xn[s];                      // wave-uniform broadcast

  // X[b, 24+t, c, 5..7] — wave-uniform address (SGPR arithmetic).
  const float* Xp = X + (((size_t)b * T_ALL + T_H) * C_ + c) * F_IN + 5;
  float* Op = out + (size_t)b * (T_FC * C_) + c;

  float* mysH = sH + wid * HID;
  const float4* mysH4 = reinterpret_cast<const float4*>(mysH);

  float x1 = Xp[0];
  float x2 = Xp[1];
  float x3 = Xp[2];

#pragma unroll 1
  for (int t = 0; t < T_FC; ++t) {
    // Prefetch next step's exogenous inputs (uniform loads; latency hides
    // under the ~460-cycle step body).
    const float* Xn = Xp + ((t < T_FC - 1) ? (C_ * F_IN) : 0);
    const float p1 = Xn[0];
    const float p2 = Xn[1];
    const float p3 = Xn[2];

    // Publish this step's h; in-order DS pipe + compiler lgkmcnt ordering
    // make write->broadcast-read safe within the wave (no barrier needed,
    // the region is wave-private).
    mysH[lane] = h;

    float gr = br, gz = bz, gn = bhn;
#define DOT(i) { const float4 hv = mysH4[i];                                   \
    gr += hv.x * wr##i.x + hv.y * wr##i.y + hv.z * wr##i.z + hv.w * wr##i.w;   \
    gz += hv.x * wz##i.x + hv.y * wz##i.y + hv.z * wz##i.z + hv.w * wz##i.w;   \
    gn += hv.x * wn##i.x + hv.y * wn##i.y + hv.z * wn##i.z + hv.w * wn##i.w; }
    REP16(DOT)
#undef DOT

    // Input contributions (xp from the previous step's reduction lands here —
    // after the DOT phase, so the butterfly latency is overlapped).
    gr += xp * wcr.x + x1 * wcr.y + x2 * wcr.z + x3 * wcr.w;
    gz += xp * wcz.x + x1 * wcz.y + x2 * wcz.z + x3 * wcz.w;
    float in_ = bcn + xp * wcn.x + x1 * wcn.y + x2 * wcn.z + x3 * wcn.w;

    const float r = fast_sigmoid(gr);
    const float z = fast_sigmoid(gz);
    const float n = fast_tanh(in_ + r * gn);
    h = (1.0f - z) * n + z * h;

    // o = sum_u h_u * Wo_u + bo  — butterfly leaves the sum in ALL lanes,
    // which doubles as the xp feedback for the next step.
    float po = h * wo;
    po += __shfl_xor(po, 1, 64);
    po += __shfl_xor(po, 2, 64);
    po += __shfl_xor(po, 4, 64);
    po += __shfl_xor(po, 8, 64);
    po += __shfl_xor(po, 16, 64);
    po += __shfl_xor(po, 32, 64);
    const float o = po + bo;

    if (lane == 0) *Op = o;
    Op += C_;
    xp = o;
    x1 = p1;
    x2 = p2;
    x3 = p3;
    Xp = Xn;
  }
}

extern "C" void kernel_launch(void* const* d_in, const int* in_sizes, int n_in,
                              void* d_out, int out_size, void* d_ws,
                              size_t ws_size, hipStream_t stream) {
  const float* X     = (const float*)d_in[0];
  const float* H     = (const float*)d_in[1];
  const float* xn    = (const float*)d_in[2];
  const float* W_in  = (const float*)d_in[3];
  const float* b_in  = (const float*)d_in[4];
  const float* W_ih  = (const float*)d_in[5];
  const float* W_hh  = (const float*)d_in[6];
  const float* b_ih  = (const float*)d_in[7];
  const float* b_hh  = (const float*)d_in[8];
  const float* W_out = (const float*)d_in[9];
  const float* b_out = (const float*)d_in[10];
  float* out = (float*)d_out;
  float* ws  = (float*)d_ws;

  setup_kernel<<<1, 192, 0, stream>>>(W_in, b_in, W_ih, b_ih, ws);
  // One wave per sequence, 4 waves (4 sequences) per 256-thread block.
  gru_kernel<<<NSEQ / 4, 256, 0, stream>>>(X, H, xn, W_hh, b_hh, W_out,
                                           b_out, ws, out);
}